// Round 8
// baseline (566.833 us; speedup 1.0000x reference)
//
#include <hip/hip_runtime.h>

#define NB 4
#define NP 900
#define ND 512
#define NH 8
#define NDK 64
#define NROWS (NB*NP)          // 3600
#define SSZ (NP*NP)            // 810000
#define NBH (NB*NH)            // 32
#define SIDE 30

typedef unsigned short ushort_t;
typedef unsigned char uchar_t;
typedef unsigned long long u64_t;
typedef __attribute__((ext_vector_type(4)))  short  s4v;
typedef __attribute__((ext_vector_type(8)))  short  s8v;
typedef __attribute__((ext_vector_type(8)))  _Float16 h8v;
typedef __attribute__((ext_vector_type(4)))  float  f4v;
typedef __attribute__((ext_vector_type(16))) float  f16v;

__device__ __forceinline__ ushort_t f2h(float f) {
    union { _Float16 h; ushort_t u; } c; c.h = (_Float16)f; return c.u;
}
__device__ __forceinline__ float h2f(ushort_t u) {
    union { _Float16 h; ushort_t u; } c; c.u = u; return (float)c.h;
}
__device__ __forceinline__ h8v mk8(s4v lo, s4v hi) {
    union { s8v s; h8v h; } c;
    c.s = __builtin_shufflevector(lo, hi, 0, 1, 2, 3, 4, 5, 6, 7);
    return c.h;
}
// order-preserving f32 -> u32 (total order; equal floats -> equal codes)
__device__ __forceinline__ unsigned int fenc(float v) {
    unsigned int b = __float_as_uint(v);
    return (b & 0x80000000u) ? ~b : (b | 0x80000000u);
}

// ---------------- projection: O[b,h,p,c] = sum_k X[b,p,k] * W[h*64+c,k] + bias (exact f32) -----
__global__ __launch_bounds__(256) void proj_kernel(
    const float* __restrict__ query, const float* __restrict__ key_t,
    const float* __restrict__ Wq, const float* __restrict__ bq,
    const float* __restrict__ Wk, const float* __restrict__ bk,
    float* __restrict__ Qo, float* __restrict__ Ko)
{
    const float *X, *W, *bias;
    float* O;
    if (blockIdx.z == 0) { X = query; W = Wq; bias = bq; O = Qo; }
    else                 { X = key_t; W = Wk; bias = bk; O = Ko; }

    __shared__ __align__(16) float As[16][68];
    __shared__ __align__(16) float Bs[16][68];

    const int i0 = blockIdx.x * 64;
    const int h  = blockIdx.y;
    const int j0 = h * 64;
    const int tid = threadIdx.x;
    const int tx = tid & 15, ty = tid >> 4;

    float acc[4][4] = {};

    for (int k0 = 0; k0 < ND; k0 += 16) {
        const int r  = tid >> 2;
        const int kk = (tid & 3) * 4;
        float4 av = make_float4(0.f, 0.f, 0.f, 0.f);
        const int gi = i0 + r;
        if (gi < NROWS) av = *(const float4*)(X + (size_t)gi * ND + k0 + kk);
        As[kk+0][r] = av.x; As[kk+1][r] = av.y; As[kk+2][r] = av.z; As[kk+3][r] = av.w;
        const float4 bv = *(const float4*)(W + (size_t)(j0 + r) * ND + k0 + kk);
        Bs[kk+0][r] = bv.x; Bs[kk+1][r] = bv.y; Bs[kk+2][r] = bv.z; Bs[kk+3][r] = bv.w;
        __syncthreads();
        #pragma unroll
        for (int k = 0; k < 16; ++k) {
            const float4 a4 = *(const float4*)&As[k][ty*4];
            const float4 b4 = *(const float4*)&Bs[k][tx*4];
            const float aa[4] = {a4.x, a4.y, a4.z, a4.w};
            const float bb[4] = {b4.x, b4.y, b4.z, b4.w};
            #pragma unroll
            for (int ii = 0; ii < 4; ++ii)
                #pragma unroll
                for (int jj = 0; jj < 4; ++jj)
                    acc[ii][jj] = fmaf(aa[ii], bb[jj], acc[ii][jj]);
        }
        __syncthreads();
    }

    #pragma unroll
    for (int ii = 0; ii < 4; ++ii) {
        const int gi = i0 + ty*4 + ii;
        if (gi >= NROWS) continue;
        const int b = gi / NP, p = gi - b * NP;
        float4 o;
        o.x = acc[ii][0] + bias[j0 + tx*4 + 0];
        o.y = acc[ii][1] + bias[j0 + tx*4 + 1];
        o.z = acc[ii][2] + bias[j0 + tx*4 + 2];
        o.w = acc[ii][3] + bias[j0 + tx*4 + 3];
        *(float4*)(O + ((size_t)(b*NH + h)*NP + p)*NDK + tx*4) = o;
    }
}

// ---------------- scores (f32 acc, 64x64 tile) + fused exact argmax; stores S as fp16 ---------
__global__ __launch_bounds__(256) void scores_kernel(
    const float* __restrict__ Q, const float* __restrict__ K, ushort_t* __restrict__ Sh,
    u64_t* __restrict__ amax)
{
    __shared__ __align__(16) float Qs[64][68];
    __shared__ __align__(16) float Ks[64][68];
    __shared__ u64_t amax_s[64];

    const int bh = blockIdx.z;
    const int q0 = blockIdx.x * 64;
    const int p0 = blockIdx.y * 64;
    const float* Qb = Q + (size_t)bh * NP * NDK;
    const float* Kb = K + (size_t)bh * NP * NDK;
    const int tid = threadIdx.x;
    const int tx = tid & 15, ty = tid >> 4;
    const int r = tid >> 2, l = tid & 3;

    if (tid < 64) amax_s[tid] = 0ull;

    #pragma unroll
    for (int u = 0; u < 4; ++u) {
        const int k = (l + 4*u) * 4;
        float4 qv = make_float4(0.f,0.f,0.f,0.f), kv = make_float4(0.f,0.f,0.f,0.f);
        if (p0 + r < NP) qv = *(const float4*)(Qb + (size_t)(p0 + r) * NDK + k);
        if (q0 + r < NP) kv = *(const float4*)(Kb + (size_t)(q0 + r) * NDK + k);
        Qs[k+0][r]=qv.x; Qs[k+1][r]=qv.y; Qs[k+2][r]=qv.z; Qs[k+3][r]=qv.w;
        Ks[k+0][r]=kv.x; Ks[k+1][r]=kv.y; Ks[k+2][r]=kv.z; Ks[k+3][r]=kv.w;
    }
    __syncthreads();

    float acc[4][4] = {};
    #pragma unroll 8
    for (int k = 0; k < NDK; ++k) {
        const float4 a4 = *(const float4*)&Qs[k][ty*4];
        const float4 b4 = *(const float4*)&Ks[k][tx*4];
        const float aa[4] = {a4.x, a4.y, a4.z, a4.w};
        const float bb[4] = {b4.x, b4.y, b4.z, b4.w};
        #pragma unroll
        for (int ii = 0; ii < 4; ++ii)
            #pragma unroll
            for (int jj = 0; jj < 4; ++jj)
                acc[ii][jj] = fmaf(aa[ii], bb[jj], acc[ii][jj]);
    }

    // store S as fp16 (argmax below uses exact f32 acc; rounding can't flip it)
    const int gq0 = q0 + tx*4;
    #pragma unroll
    for (int ii = 0; ii < 4; ++ii) {
        const int gp = p0 + ty*4 + ii;
        if (gp < NP && gq0 < NP) {     // 900 % 4 == 0 -> 4-col group all-or-nothing
            uint2 wv;
            wv.x = (unsigned)f2h(acc[ii][0]) | ((unsigned)f2h(acc[ii][1]) << 16);
            wv.y = (unsigned)f2h(acc[ii][2]) | ((unsigned)f2h(acc[ii][3]) << 16);
            *(uint2*)(Sh + (size_t)bh*SSZ + (size_t)gp*NP + gq0) = wv;
        }
    }

    // fused argmax over p: key = (enc(v)<<32) | (899-p)  -> max = (max v, first p)
    #pragma unroll
    for (int jj = 0; jj < 4; ++jj) {
        const int gq = gq0 + jj;
        if (gq >= NP) continue;
        u64_t key = 0ull;
        #pragma unroll
        for (int ii = 0; ii < 4; ++ii) {
            const int gp = p0 + ty*4 + ii;
            if (gp >= NP) continue;
            const u64_t kk = ((u64_t)fenc(acc[ii][jj]) << 32) | (unsigned)(899 - gp);
            key = key > kk ? key : kk;
        }
        atomicMax(&amax_s[tx*4 + jj], key);
    }
    __syncthreads();
    if (tid < 64 && q0 + tid < NP)
        atomicMax(&amax[(size_t)bh*NP + q0 + tid], amax_s[tid]);
}

// ---------------- decode packed argmax -> packed (ix, iy) bytes ----------
__global__ __launch_bounds__(256) void decode_kernel(
    const u64_t* __restrict__ amax, uchar_t* __restrict__ gidx)
{
    const int t = blockIdx.x * 256 + threadIdx.x;
    if (t >= NBH * NP) return;
    const int idx = 899 - (int)(unsigned)(amax[t] & 0xFFFFFFFFull);
    gidx[2*t]   = (uchar_t)(idx % SIDE);
    gidx[2*t+1] = (uchar_t)(idx / SIDE);
}

// ---------------- gaussian modulate + scale + softmax; fp16 S in, fp16 ch-last S2 out ---------
__global__ __launch_bounds__(256) void modulate_softmax_kernel(
    const ushort_t* __restrict__ S, const uchar_t* __restrict__ gidx, ushort_t* __restrict__ S2)
{
    __shared__ __align__(16) ushort_t ob[NP][NH];  // 14.4 KB
    __shared__ float TX[SIDE], TY[SIDE];

    const int p = blockIdx.x;
    const int b = blockIdx.y;
    const int tid = threadIdx.x;
    const int lane = tid & 63;
    const int w = tid >> 6;

    const float ax = -1.f + (2.f/29.f) * (float)(p % SIDE);
    const float ay = -1.f + (2.f/29.f) * (float)(p / SIDE);

    if (tid < SIDE) {
        const float d = ax - (float)tid;
        TX[tid] = __expf(-d*d * 0.02f);                 // 1/(2*sigma^2), sigma=5
    } else if (tid >= 64 && tid < 64 + SIDE) {
        const int j = tid - 64;
        const float d = ay - (float)j;
        TY[j] = __expf(-d*d * 0.02f);
    }
    __syncthreads();

    #pragma unroll 1
    for (int hh = 0; hh < 2; ++hh) {
        const int h = w + hh*4;
        const ushort_t* row = S + (size_t)(b*NH + h)*SSZ + (size_t)p*NP;
        const uchar_t* gp = gidx + (size_t)(b*NH + h)*NP*2;

        float rv[16];
        float lmax = -3.4e38f;
        #pragma unroll
        for (int i = 0; i < 8; ++i) {
            const int q2 = 2*lane + 128*i;      // even; pair (q2, q2+1)
            float v0 = -3.4e38f, v1 = -3.4e38f;
            if (q2 < NP) {                       // NP even -> pair fully valid
                const unsigned u = *(const unsigned*)(row + q2);
                const uchar4 g4 = *(const uchar4*)(gp + 2*q2);   // ix0,iy0,ix1,iy1
                v0 = h2f((ushort_t)(u & 0xFFFFu)) * TX[g4.x] * TY[g4.y] * 0.125f;
                v1 = h2f((ushort_t)(u >> 16))     * TX[g4.z] * TY[g4.w] * 0.125f;
            }
            rv[2*i]   = v0;
            rv[2*i+1] = v1;
            lmax = fmaxf(lmax, fmaxf(v0, v1));
        }
        #pragma unroll
        for (int off = 32; off > 0; off >>= 1)
            lmax = fmaxf(lmax, __shfl_xor(lmax, off, 64));

        float lsum = 0.f;
        #pragma unroll
        for (int i = 0; i < 16; ++i) {
            const int q = 2*lane + 128*(i >> 1) + (i & 1);
            const float e = (q < NP) ? __expf(rv[i] - lmax) : 0.f;
            rv[i] = e;
            lsum += e;
        }
        #pragma unroll
        for (int off = 32; off > 0; off >>= 1)
            lsum += __shfl_xor(lsum, off, 64);
        const float inv = 1.f / lsum;

        #pragma unroll
        for (int i = 0; i < 8; ++i) {
            const int q2 = 2*lane + 128*i;
            if (q2 < NP) {
                ob[q2][h]   = f2h(rv[2*i]   * inv);
                ob[q2+1][h] = f2h(rv[2*i+1] * inv);
            }
        }
    }
    __syncthreads();
    for (int q = tid; q < NP; q += 256)
        *(uint4*)(S2 + (((size_t)b*NP + p)*NP + q)*NH) = *(const uint4*)&ob[q][0];
}

// ---------------- weight fragment prep (B-operand layouts, fp16) ----------------
__global__ void prep_weights_kernel(
    const float* __restrict__ c1w, const float* __restrict__ c2w,
    ushort_t* __restrict__ w1b, ushort_t* __restrict__ w2b)
{
    const int tid = threadIdx.x;
    for (int i = tid; i < 5*64; i += 256) {
        const int c = i >> 6, l = i & 63;
        const int oc = l & 31, hf = l >> 5;
        #pragma unroll
        for (int j = 0; j < 8; ++j) {
            float wv;
            if (c < 4)      wv = c1w[(oc*8 + j)*9 + (2*c + hf)];
            else            wv = hf ? 0.f : c1w[(oc*8 + j)*9 + 8];
            w1b[(i)*8 + j] = f2h(wv);
        }
    }
    for (int i = tid; i < 9*64; i += 256) {
        const int t = i >> 6, l = i & 63;
        const int n = l & 15, qd = l >> 4;
        #pragma unroll
        for (int j = 0; j < 8; ++j) {
            const int k = qd*8 + j;
            const float wv = (n < 8) ? c2w[(n*32 + k)*9 + t] : 0.f;
            w2b[(i)*8 + j] = f2h(wv);
        }
    }
}

// ---------------- MFMA fused conv1+conv2+value-reduce (fp16) ----------------
// Per-wave 30(x) x 9(y) stripe. A-fragments loaded DIRECTLY from global S2 (ch-last, 16 B
// contiguous -> dwordx4 on the VMEM pipe); LDS holds only the per-wave c1 row buffer.
// DS pipe and VMEM pipe run in parallel; barrier-free; LDS 9.8 KB.
__global__ __launch_bounds__(256, 6) void conv_mfma_kernel(
    const ushort_t* __restrict__ S2, const ushort_t* __restrict__ w1b,
    const ushort_t* __restrict__ w2b,
    const float* __restrict__ b1, const float* __restrict__ b2,
    const float* __restrict__ value, float* __restrict__ out)
{
    __shared__ __align__(16) ushort_t c1row[4][34][36];     // 9,792 B: one c1 row per wave

    const int tid  = threadIdx.x;
    const int lane = tid & 63;
    const int w    = tid >> 6;
    const int b    = blockIdx.z;
    const int gx0  = blockIdx.x * 30;
    const int gy0w = blockIdx.y * 36 + w * 9;

    // zero guard rows x=32,33 (read by group-1 fragments; results discarded via vseg=0)
    c1row[w][32 + (lane >> 5)][lane & 31] = 0;

    // ---- weight fragments (global, L2-cached) ----
    h8v w1f[5], w2f[9];
    #pragma unroll
    for (int c = 0; c < 5; ++c) w1f[c] = *(const h8v*)(w1b + ((size_t)c*64 + lane)*8);
    #pragma unroll
    for (int t = 0; t < 9; ++t) w2f[t] = *(const h8v*)(w2b + ((size_t)t*64 + lane)*8);

    const float b1v = b1[lane & 31];
    const float b2v = ((lane & 15) < 8) ? b2[lane & 15] : 0.f;

    const int m    = lane & 31;    // conv1 A-frag M index (c1 x)
    const int half = lane >> 5;    // conv1 K-half (tap-in-pair)
    const int m16  = lane & 15;    // conv2 A-frag M index
    const int qd   = lane >> 4;    // conv2 K-quad

    float vseg[2][4];
    #pragma unroll
    for (int g = 0; g < 2; ++g)
        #pragma unroll
        for (int r = 0; r < 4; ++r) {
            const int ql = g*16 + qd*4 + r;
            vseg[g][r] = (ql < 30) ? value[b*NP + gx0 + ql] : 0.f;
        }

    // A-fragment: contiguous 16 B of S2 at image pixel (gp, gq), zero outside image
    auto ldg = [&](int y, int x) -> h8v {
        const int gp = gy0w - 2 + y;
        const int gq = gx0 - 2 + x;
        h8v v = {};
        if ((unsigned)gp < (unsigned)NP && (unsigned)gq < (unsigned)NP)
            v = *(const h8v*)(S2 + (((size_t)b*NP + gp)*NP + gq)*NH);
        return v;
    };

    f4v o0[3] = {}, o1[3] = {};   // rolling accumulators, out row yo -> slot yo%3

    #pragma unroll
    for (int yc = 0; yc < 11; ++yc) {
        // ---- conv1: c1 row yc (image row gy0w-1+yc) -> c1row[w] ----
        {
            const bool rowok = (unsigned)(gy0w - 1 + yc) < (unsigned)NP;
            const h8v A0 = ldg(yc,        m + half);            // taps 0,1
            const h8v A1 = ldg(yc + half, half ? m : (m + 2));  // taps 2,3
            const h8v A2 = ldg(yc + 1,    m + 1 + half);        // taps 4,5
            const h8v A3 = ldg(yc + 2,    m + half);            // taps 6,7
            const h8v A4 = ldg(yc + 2,    m + 2);               // tap 8
            f16v acc = {};
            acc = __builtin_amdgcn_mfma_f32_32x32x16_f16(A0, w1f[0], acc, 0, 0, 0);
            acc = __builtin_amdgcn_mfma_f32_32x32x16_f16(A1, w1f[1], acc, 0, 0, 0);
            acc = __builtin_amdgcn_mfma_f32_32x32x16_f16(A2, w1f[2], acc, 0, 0, 0);
            acc = __builtin_amdgcn_mfma_f32_32x32x16_f16(A3, w1f[3], acc, 0, 0, 0);
            acc = __builtin_amdgcn_mfma_f32_32x32x16_f16(A4, w1f[4], acc, 0, 0, 0);
            #pragma unroll
            for (int r = 0; r < 16; ++r) {
                const int x_l = (r & 3) + 8*(r >> 2) + 4*half;   // D row = c1 x
                float f = fmaxf(acc[r] + b1v, 0.f);
                const bool ok = rowok && ((unsigned)(gx0 - 1 + x_l) < (unsigned)NP);
                f = ok ? f : 0.f;                                // SAME-pad: OOB c1 = 0
                c1row[w][x_l][lane & 31] = f2h(f);
            }
        }
        // same-wave LDS write->read: DS ops in order per wave; drain counter
        asm volatile("s_waitcnt lgkmcnt(0)" ::: "memory");

        // ---- conv2: read 6 fragments once, scatter into out rows yc-2..yc ----
        #pragma unroll
        for (int dx = 0; dx < 3; ++dx) {
            const int x0 = m16 + dx, x1 = 16 + m16 + dx;
            const h8v a0 = mk8(*(const s4v*)&c1row[w][x0][qd*8],
                               *(const s4v*)&c1row[w][x0][qd*8 + 4]);
            const h8v a1 = mk8(*(const s4v*)&c1row[w][x1][qd*8],
                               *(const s4v*)&c1row[w][x1][qd*8 + 4]);
            #pragma unroll
            for (int dy = 0; dy < 3; ++dy) {
                const int yo = yc - dy;
                if (yo < 0 || yo > 8) continue;
                const int sl = yo % 3;
                o0[sl] = __builtin_amdgcn_mfma_f32_16x16x32_f16(a0, w2f[dy*3+dx], o0[sl], 0, 0, 0);
                o1[sl] = __builtin_amdgcn_mfma_f32_16x16x32_f16(a1, w2f[dy*3+dx], o1[sl], 0, 0, 0);
            }
        }

        // ---- out row yc-2 complete: epilogue + reset slot ----
        if (yc >= 2) {
            const int yo = yc - 2;
            const int sl = yo % 3;
            float s = 0.f;
            const bool ocok = (lane & 15) < 8;
            #pragma unroll
            for (int r = 0; r < 4; ++r) {
                const float f0 = fmaxf(o0[sl][r] + b2v, 0.f);
                const float f1 = fmaxf(o1[sl][r] + b2v, 0.f);
                s += ocok ? f0 * vseg[0][r] : 0.f;
                s += ocok ? f1 * vseg[1][r] : 0.f;
            }
            #pragma unroll
            for (int off = 32; off > 0; off >>= 1)
                s += __shfl_down(s, off, 64);
            if (lane == 0)
                atomicAdd(out + (size_t)b*NP + (gy0w + yo), s * 0.125f);
            o0[sl] = (f4v){0.f,0.f,0.f,0.f};
            o1[sl] = (f4v){0.f,0.f,0.f,0.f};
        }
    }
}

extern "C" void kernel_launch(void* const* d_in, const int* in_sizes, int n_in,
                              void* d_out, int out_size, void* d_ws, size_t ws_size,
                              hipStream_t stream)
{
    const float* query = (const float*)d_in[0];
    const float* key_t = (const float*)d_in[1];
    const float* value = (const float*)d_in[2];
    const float* Wq    = (const float*)d_in[3];
    const float* bq    = (const float*)d_in[4];
    const float* Wk    = (const float*)d_in[5];
    const float* bk    = (const float*)d_in[6];
    const float* c1w   = (const float*)d_in[7];
    const float* c1b   = (const float*)d_in[8];
    const float* c2w   = (const float*)d_in[9];
    const float* c2b   = (const float*)d_in[10];
    float* out = (float*)d_out;

    float*    Q    = (float*)d_ws;
    float*    K    = Q + (size_t)NBH*NP*NDK;                // +1,843,200 floats
    u64_t*    amax = (u64_t*)(K + (size_t)NBH*NP*NDK);      // 32*900 u64
    uchar_t*  gidx = (uchar_t*)(amax + (size_t)NBH*NP);     // 32*900*2 B
    ushort_t* Sh   = (ushort_t*)(gidx + (size_t)NBH*NP*2 + 256);  // fp16 scores, 51.84 MB
    ushort_t* S2   = Sh + (size_t)NBH*SSZ;                  // fp16 attn ch-last, 51.84 MB
    ushort_t* w1b  = S2 + (size_t)NB*NP*NP*NH;
    ushort_t* w2b  = w1b + 5*64*8;

    hipMemsetAsync(d_out, 0, (size_t)out_size * sizeof(float), stream);
    hipMemsetAsync(amax, 0, (size_t)NBH*NP*sizeof(u64_t), stream);

    prep_weights_kernel<<<dim3(1), 256, 0, stream>>>(c1w, c2w, w1b, w2b);
    proj_kernel<<<dim3(57, 8, 2), 256, 0, stream>>>(query, key_t, Wq, bq, Wk, bk, Q, K);
    scores_kernel<<<dim3(15, 15, 32), 256, 0, stream>>>(Q, K, Sh, amax);
    decode_kernel<<<dim3(113), 256, 0, stream>>>(amax, gidx);
    modulate_softmax_kernel<<<dim3(900, 4), 256, 0, stream>>>(Sh, gidx, S2);
    conv_mfma_kernel<<<dim3(30, 25, 4), 256, 0, stream>>>(S2, w1b, w2b, c1b, c2b, value, out);
}

// Round 9
// 303.077 us; speedup vs baseline: 1.8703x; 1.8703x over previous
//
#include <hip/hip_runtime.h>

#define NB 4
#define NP 900
#define ND 512
#define NH 8
#define NDK 64
#define NROWS (NB*NP)          // 3600
#define SSZ (NP*NP)            // 810000
#define NBH (NB*NH)            // 32
#define SIDE 30

typedef unsigned short ushort_t;
typedef unsigned char uchar_t;
typedef unsigned long long u64_t;
typedef __attribute__((ext_vector_type(8)))  _Float16 h8v;
typedef __attribute__((ext_vector_type(4)))  float  f4v;
typedef __attribute__((ext_vector_type(16))) float  f16v;

__device__ __forceinline__ ushort_t f2h(float f) {
    union { _Float16 h; ushort_t u; } c; c.h = (_Float16)f; return c.u;
}
__device__ __forceinline__ float h2f(ushort_t u) {
    union { _Float16 h; ushort_t u; } c; c.u = u; return (float)c.h;
}
// order-preserving f32 -> u32 (total order; equal floats -> equal codes)
__device__ __forceinline__ unsigned int fenc(float v) {
    unsigned int b = __float_as_uint(v);
    return (b & 0x80000000u) ? ~b : (b | 0x80000000u);
}

// ---------------- projection (exact f32); also zeroes amax for the scores pass ----------
__global__ __launch_bounds__(256) void proj_kernel(
    const float* __restrict__ query, const float* __restrict__ key_t,
    const float* __restrict__ Wq, const float* __restrict__ bq,
    const float* __restrict__ Wk, const float* __restrict__ bk,
    float* __restrict__ Qo, float* __restrict__ Ko, u64_t* __restrict__ amax)
{
    const float *X, *W, *bias;
    float* O;
    if (blockIdx.z == 0) { X = query; W = Wq; bias = bq; O = Qo; }
    else                 { X = key_t; W = Wk; bias = bk; O = Ko; }

    // fused amax zeroing (ordered before scores_kernel by stream order)
    if (blockIdx.z == 0 && blockIdx.y == 0) {
        const int t = blockIdx.x * 256 + threadIdx.x;
        if (t < NBH * NP) amax[t] = 0ull;
    }

    __shared__ __align__(16) float As[16][68];
    __shared__ __align__(16) float Bs[16][68];

    const int i0 = blockIdx.x * 64;
    const int h  = blockIdx.y;
    const int j0 = h * 64;
    const int tid = threadIdx.x;
    const int tx = tid & 15, ty = tid >> 4;

    float acc[4][4] = {};

    for (int k0 = 0; k0 < ND; k0 += 16) {
        const int r  = tid >> 2;
        const int kk = (tid & 3) * 4;
        float4 av = make_float4(0.f, 0.f, 0.f, 0.f);
        const int gi = i0 + r;
        if (gi < NROWS) av = *(const float4*)(X + (size_t)gi * ND + k0 + kk);
        As[kk+0][r] = av.x; As[kk+1][r] = av.y; As[kk+2][r] = av.z; As[kk+3][r] = av.w;
        const float4 bv = *(const float4*)(W + (size_t)(j0 + r) * ND + k0 + kk);
        Bs[kk+0][r] = bv.x; Bs[kk+1][r] = bv.y; Bs[kk+2][r] = bv.z; Bs[kk+3][r] = bv.w;
        __syncthreads();
        #pragma unroll
        for (int k = 0; k < 16; ++k) {
            const float4 a4 = *(const float4*)&As[k][ty*4];
            const float4 b4 = *(const float4*)&Bs[k][tx*4];
            const float aa[4] = {a4.x, a4.y, a4.z, a4.w};
            const float bb[4] = {b4.x, b4.y, b4.z, b4.w};
            #pragma unroll
            for (int ii = 0; ii < 4; ++ii)
                #pragma unroll
                for (int jj = 0; jj < 4; ++jj)
                    acc[ii][jj] = fmaf(aa[ii], bb[jj], acc[ii][jj]);
        }
        __syncthreads();
    }

    #pragma unroll
    for (int ii = 0; ii < 4; ++ii) {
        const int gi = i0 + ty*4 + ii;
        if (gi >= NROWS) continue;
        const int b = gi / NP, p = gi - b * NP;
        float4 o;
        o.x = acc[ii][0] + bias[j0 + tx*4 + 0];
        o.y = acc[ii][1] + bias[j0 + tx*4 + 1];
        o.z = acc[ii][2] + bias[j0 + tx*4 + 2];
        o.w = acc[ii][3] + bias[j0 + tx*4 + 3];
        *(float4*)(O + ((size_t)(b*NH + h)*NP + p)*NDK + tx*4) = o;
    }
}

// ---------------- scores (f32 acc, 64x64 tile) + fused exact argmax; stores S as fp16 ---------
__global__ __launch_bounds__(256) void scores_kernel(
    const float* __restrict__ Q, const float* __restrict__ K, ushort_t* __restrict__ Sh,
    u64_t* __restrict__ amax)
{
    __shared__ __align__(16) float Qs[64][68];
    __shared__ __align__(16) float Ks[64][68];
    __shared__ u64_t amax_s[64];

    const int bh = blockIdx.z;
    const int q0 = blockIdx.x * 64;
    const int p0 = blockIdx.y * 64;
    const float* Qb = Q + (size_t)bh * NP * NDK;
    const float* Kb = K + (size_t)bh * NP * NDK;
    const int tid = threadIdx.x;
    const int tx = tid & 15, ty = tid >> 4;
    const int r = tid >> 2, l = tid & 3;

    if (tid < 64) amax_s[tid] = 0ull;

    #pragma unroll
    for (int u = 0; u < 4; ++u) {
        const int k = (l + 4*u) * 4;
        float4 qv = make_float4(0.f,0.f,0.f,0.f), kv = make_float4(0.f,0.f,0.f,0.f);
        if (p0 + r < NP) qv = *(const float4*)(Qb + (size_t)(p0 + r) * NDK + k);
        if (q0 + r < NP) kv = *(const float4*)(Kb + (size_t)(q0 + r) * NDK + k);
        Qs[k+0][r]=qv.x; Qs[k+1][r]=qv.y; Qs[k+2][r]=qv.z; Qs[k+3][r]=qv.w;
        Ks[k+0][r]=kv.x; Ks[k+1][r]=kv.y; Ks[k+2][r]=kv.z; Ks[k+3][r]=kv.w;
    }
    __syncthreads();

    float acc[4][4] = {};
    #pragma unroll 8
    for (int k = 0; k < NDK; ++k) {
        const float4 a4 = *(const float4*)&Qs[k][ty*4];
        const float4 b4 = *(const float4*)&Ks[k][tx*4];
        const float aa[4] = {a4.x, a4.y, a4.z, a4.w};
        const float bb[4] = {b4.x, b4.y, b4.z, b4.w};
        #pragma unroll
        for (int ii = 0; ii < 4; ++ii)
            #pragma unroll
            for (int jj = 0; jj < 4; ++jj)
                acc[ii][jj] = fmaf(aa[ii], bb[jj], acc[ii][jj]);
    }

    // store S as fp16 (argmax below uses exact f32 acc; rounding can't flip it)
    const int gq0 = q0 + tx*4;
    #pragma unroll
    for (int ii = 0; ii < 4; ++ii) {
        const int gp = p0 + ty*4 + ii;
        if (gp < NP && gq0 < NP) {     // 900 % 4 == 0 -> 4-col group all-or-nothing
            uint2 wv;
            wv.x = (unsigned)f2h(acc[ii][0]) | ((unsigned)f2h(acc[ii][1]) << 16);
            wv.y = (unsigned)f2h(acc[ii][2]) | ((unsigned)f2h(acc[ii][3]) << 16);
            *(uint2*)(Sh + (size_t)bh*SSZ + (size_t)gp*NP + gq0) = wv;
        }
    }

    // fused argmax over p: key = (enc(v)<<32) | (899-p)  -> max = (max v, first p)
    #pragma unroll
    for (int jj = 0; jj < 4; ++jj) {
        const int gq = gq0 + jj;
        if (gq >= NP) continue;
        u64_t key = 0ull;
        #pragma unroll
        for (int ii = 0; ii < 4; ++ii) {
            const int gp = p0 + ty*4 + ii;
            if (gp >= NP) continue;
            const u64_t kk = ((u64_t)fenc(acc[ii][jj]) << 32) | (unsigned)(899 - gp);
            key = key > kk ? key : kk;
        }
        atomicMax(&amax_s[tx*4 + jj], key);
    }
    __syncthreads();
    if (tid < 64 && q0 + tid < NP)
        atomicMax(&amax[(size_t)bh*NP + q0 + tid], amax_s[tid]);
}

// ---------------- decode packed argmax -> packed (ix, iy) bytes ----------
__global__ __launch_bounds__(256) void decode_kernel(
    const u64_t* __restrict__ amax, uchar_t* __restrict__ gidx)
{
    const int t = blockIdx.x * 256 + threadIdx.x;
    if (t >= NBH * NP) return;
    const int idx = 899 - (int)(unsigned)(amax[t] & 0xFFFFFFFFull);
    gidx[2*t]   = (uchar_t)(idx % SIDE);
    gidx[2*t+1] = (uchar_t)(idx / SIDE);
}

// ---------------- gaussian modulate + scale + softmax; fp16 S in, fp16 ch-last S2 out ---------
// Also zeroes `out` for the conv pass (p==0 blocks; ordered before conv by stream order).
__global__ __launch_bounds__(256) void modulate_softmax_kernel(
    const ushort_t* __restrict__ S, const uchar_t* __restrict__ gidx, ushort_t* __restrict__ S2,
    float* __restrict__ out)
{
    __shared__ __align__(16) ushort_t ob[NP][NH];  // 14.4 KB
    __shared__ float TX[SIDE], TY[SIDE];

    const int p = blockIdx.x;
    const int b = blockIdx.y;
    const int tid = threadIdx.x;
    const int lane = tid & 63;
    const int w = tid >> 6;

    if (p == 0)
        for (int q = tid; q < NP; q += 256) out[(size_t)b*NP + q] = 0.f;

    const float ax = -1.f + (2.f/29.f) * (float)(p % SIDE);
    const float ay = -1.f + (2.f/29.f) * (float)(p / SIDE);

    if (tid < SIDE) {
        const float d = ax - (float)tid;
        TX[tid] = __expf(-d*d * 0.02f);                 // 1/(2*sigma^2), sigma=5
    } else if (tid >= 64 && tid < 64 + SIDE) {
        const int j = tid - 64;
        const float d = ay - (float)j;
        TY[j] = __expf(-d*d * 0.02f);
    }
    __syncthreads();

    #pragma unroll 1
    for (int hh = 0; hh < 2; ++hh) {
        const int h = w + hh*4;
        const ushort_t* row = S + (size_t)(b*NH + h)*SSZ + (size_t)p*NP;
        const uchar_t* gp = gidx + (size_t)(b*NH + h)*NP*2;

        float rv[16];
        float lmax = -3.4e38f;
        #pragma unroll
        for (int i = 0; i < 8; ++i) {
            const int q2 = 2*lane + 128*i;      // even; pair (q2, q2+1)
            float v0 = -3.4e38f, v1 = -3.4e38f;
            if (q2 < NP) {                       // NP even -> pair fully valid
                const unsigned u = *(const unsigned*)(row + q2);
                const uchar4 g4 = *(const uchar4*)(gp + 2*q2);   // ix0,iy0,ix1,iy1
                v0 = h2f((ushort_t)(u & 0xFFFFu)) * TX[g4.x] * TY[g4.y] * 0.125f;
                v1 = h2f((ushort_t)(u >> 16))     * TX[g4.z] * TY[g4.w] * 0.125f;
            }
            rv[2*i]   = v0;
            rv[2*i+1] = v1;
            lmax = fmaxf(lmax, fmaxf(v0, v1));
        }
        #pragma unroll
        for (int off = 32; off > 0; off >>= 1)
            lmax = fmaxf(lmax, __shfl_xor(lmax, off, 64));

        float lsum = 0.f;
        #pragma unroll
        for (int i = 0; i < 16; ++i) {
            const int q = 2*lane + 128*(i >> 1) + (i & 1);
            const float e = (q < NP) ? __expf(rv[i] - lmax) : 0.f;
            rv[i] = e;
            lsum += e;
        }
        #pragma unroll
        for (int off = 32; off > 0; off >>= 1)
            lsum += __shfl_xor(lsum, off, 64);
        const float inv = 1.f / lsum;

        #pragma unroll
        for (int i = 0; i < 8; ++i) {
            const int q2 = 2*lane + 128*i;
            if (q2 < NP) {
                ob[q2][h]   = f2h(rv[2*i]   * inv);
                ob[q2+1][h] = f2h(rv[2*i+1] * inv);
            }
        }
    }
    __syncthreads();
    for (int q = tid; q < NP; q += 256)
        *(uint4*)(S2 + (((size_t)b*NP + p)*NP + q)*NH) = *(const uint4*)&ob[q][0];
}

// ---------------- weight fragment prep (B-operand layouts, fp16) ----------------
__global__ void prep_weights_kernel(
    const float* __restrict__ c1w, const float* __restrict__ c2w,
    ushort_t* __restrict__ w1b, ushort_t* __restrict__ w2b)
{
    const int tid = threadIdx.x;
    for (int i = tid; i < 5*64; i += 256) {
        const int c = i >> 6, l = i & 63;
        const int oc = l & 31, hf = l >> 5;
        #pragma unroll
        for (int j = 0; j < 8; ++j) {
            float wv;
            if (c < 4)      wv = c1w[(oc*8 + j)*9 + (2*c + hf)];
            else            wv = hf ? 0.f : c1w[(oc*8 + j)*9 + 8];
            w1b[(i)*8 + j] = f2h(wv);
        }
    }
    for (int i = tid; i < 9*64; i += 256) {
        const int t = i >> 6, l = i & 63;
        const int n = l & 15, qd = l >> 4;
        #pragma unroll
        for (int j = 0; j < 8; ++j) {
            const int k = qd*8 + j;
            const float wv = (n < 8) ? c2w[(n*32 + k)*9 + t] : 0.f;
            w2b[(i)*8 + j] = f2h(wv);
        }
    }
}

// ---------------- MFMA fused conv1+conv2+value-reduce (fp16) ----------------
// R4-proven layout: single a_s array (16 B/pixel -> one ds_read_b128 per A-fragment),
// c1row stride 80 B (16B-aligned -> conv2 fragment = single ds_read_b128).
// Per-wave 30(x) x 9(y) stripe; rolling conv2 accumulators; barrier-free main loop.
__global__ __launch_bounds__(256, 4) void conv_mfma_kernel(
    const ushort_t* __restrict__ S2, const ushort_t* __restrict__ w1b,
    const ushort_t* __restrict__ w2b,
    const float* __restrict__ b1, const float* __restrict__ b2,
    const float* __restrict__ value, float* __restrict__ out)
{
    __shared__ __align__(16) ushort_t a_s[4][13][34][8];    // 28,288 B: attn tile, ch-last fp16
    __shared__ __align__(16) ushort_t c1row[4][34][40];     // 10,880 B: one c1 row per wave

    const int tid  = threadIdx.x;
    const int lane = tid & 63;
    const int w    = tid >> 6;
    const int b    = blockIdx.z;
    const int gx0  = blockIdx.x * 30;
    const int gy0w = blockIdx.y * 36 + w * 9;

    // zero guard rows x=32,33 (read by group-1 fragments; results discarded via vseg=0)
    c1row[w][32 + (lane >> 5)][lane & 31] = 0;

    // ---- stage attn tile (zeros outside image); per-wave, no barrier ----
    for (int i = lane; i < 13*34; i += 64) {
        const int ai = i / 34, xi = i - ai*34;
        const int gp = gy0w - 2 + ai, gq = gx0 - 2 + xi;
        uint4 v = make_uint4(0u,0u,0u,0u);
        if ((unsigned)gp < (unsigned)NP && (unsigned)gq < (unsigned)NP)
            v = *(const uint4*)(S2 + (((size_t)b*NP + gp)*NP + gq)*NH);
        *(uint4*)&a_s[w][ai][xi][0] = v;
    }

    // ---- weight fragments (global, L2-cached) ----
    h8v w1f[5], w2f[9];
    #pragma unroll
    for (int c = 0; c < 5; ++c) w1f[c] = *(const h8v*)(w1b + ((size_t)c*64 + lane)*8);
    #pragma unroll
    for (int t = 0; t < 9; ++t) w2f[t] = *(const h8v*)(w2b + ((size_t)t*64 + lane)*8);

    const float b1v = b1[lane & 31];
    const float b2v = ((lane & 15) < 8) ? b2[lane & 15] : 0.f;

    const int m    = lane & 31;    // conv1 A-frag M index (c1 x)
    const int half = lane >> 5;    // conv1 K-half (tap-in-pair)
    const int m16  = lane & 15;    // conv2 A-frag M index
    const int qd   = lane >> 4;    // conv2 K-quad

    float vseg[2][4];
    #pragma unroll
    for (int g = 0; g < 2; ++g)
        #pragma unroll
        for (int r = 0; r < 4; ++r) {
            const int ql = g*16 + qd*4 + r;
            vseg[g][r] = (ql < 30) ? value[b*NP + gx0 + ql] : 0.f;
        }

    auto lda = [&](int y, int x) -> h8v {
        return *(const h8v*)&a_s[w][y][x][0];   // single ds_read_b128
    };

    f4v o0[3] = {}, o1[3] = {};   // rolling accumulators, out row yo -> slot yo%3

    #pragma unroll
    for (int yc = 0; yc < 11; ++yc) {
        // ---- conv1: c1 row yc (image row gy0w-1+yc) -> c1row[w] ----
        {
            const bool rowok = (unsigned)(gy0w - 1 + yc) < (unsigned)NP;
            const h8v A0 = lda(yc,        m + half);            // taps 0,1
            const h8v A1 = lda(yc + half, half ? m : (m + 2));  // taps 2,3
            const h8v A2 = lda(yc + 1,    m + 1 + half);        // taps 4,5
            const h8v A3 = lda(yc + 2,    m + half);            // taps 6,7
            const h8v A4 = lda(yc + 2,    m + 2);               // tap 8
            f16v acc = {};
            acc = __builtin_amdgcn_mfma_f32_32x32x16_f16(A0, w1f[0], acc, 0, 0, 0);
            acc = __builtin_amdgcn_mfma_f32_32x32x16_f16(A1, w1f[1], acc, 0, 0, 0);
            acc = __builtin_amdgcn_mfma_f32_32x32x16_f16(A2, w1f[2], acc, 0, 0, 0);
            acc = __builtin_amdgcn_mfma_f32_32x32x16_f16(A3, w1f[3], acc, 0, 0, 0);
            acc = __builtin_amdgcn_mfma_f32_32x32x16_f16(A4, w1f[4], acc, 0, 0, 0);
            #pragma unroll
            for (int r = 0; r < 16; ++r) {
                const int x_l = (r & 3) + 8*(r >> 2) + 4*half;   // D row = c1 x
                float f = fmaxf(acc[r] + b1v, 0.f);
                const bool ok = rowok && ((unsigned)(gx0 - 1 + x_l) < (unsigned)NP);
                f = ok ? f : 0.f;                                // SAME-pad: OOB c1 = 0
                c1row[w][x_l][lane & 31] = f2h(f);
            }
        }
        // same-wave LDS write->read: DS ops in order per wave; drain counter
        asm volatile("s_waitcnt lgkmcnt(0)" ::: "memory");

        // ---- conv2: read 6 fragments once (aligned b128), scatter into rows yc-2..yc ----
        #pragma unroll
        for (int dx = 0; dx < 3; ++dx) {
            const int x0 = m16 + dx, x1 = 16 + m16 + dx;
            const h8v a0 = *(const h8v*)&c1row[w][x0][qd*8];
            const h8v a1 = *(const h8v*)&c1row[w][x1][qd*8];
            #pragma unroll
            for (int dy = 0; dy < 3; ++dy) {
                const int yo = yc - dy;
                if (yo < 0 || yo > 8) continue;
                const int sl = yo % 3;
                o0[sl] = __builtin_amdgcn_mfma_f32_16x16x32_f16(a0, w2f[dy*3+dx], o0[sl], 0, 0, 0);
                o1[sl] = __builtin_amdgcn_mfma_f32_16x16x32_f16(a1, w2f[dy*3+dx], o1[sl], 0, 0, 0);
            }
        }

        // ---- out row yc-2 complete: epilogue + reset slot ----
        if (yc >= 2) {
            const int yo = yc - 2;
            const int sl = yo % 3;
            float s = 0.f;
            const bool ocok = (lane & 15) < 8;
            #pragma unroll
            for (int r = 0; r < 4; ++r) {
                const float f0 = fmaxf(o0[sl][r] + b2v, 0.f);
                const float f1 = fmaxf(o1[sl][r] + b2v, 0.f);
                s += ocok ? f0 * vseg[0][r] : 0.f;
                s += ocok ? f1 * vseg[1][r] : 0.f;
            }
            #pragma unroll
            for (int off = 32; off > 0; off >>= 1)
                s += __shfl_down(s, off, 64);
            if (lane == 0)
                atomicAdd(out + (size_t)b*NP + (gy0w + yo), s * 0.125f);
            o0[sl] = (f4v){0.f,0.f,0.f,0.f};
            o1[sl] = (f4v){0.f,0.f,0.f,0.f};
        }
    }
}

extern "C" void kernel_launch(void* const* d_in, const int* in_sizes, int n_in,
                              void* d_out, int out_size, void* d_ws, size_t ws_size,
                              hipStream_t stream)
{
    const float* query = (const float*)d_in[0];
    const float* key_t = (const float*)d_in[1];
    const float* value = (const float*)d_in[2];
    const float* Wq    = (const float*)d_in[3];
    const float* bq    = (const float*)d_in[4];
    const float* Wk    = (const float*)d_in[5];
    const float* bk    = (const float*)d_in[6];
    const float* c1w   = (const float*)d_in[7];
    const float* c1b   = (const float*)d_in[8];
    const float* c2w   = (const float*)d_in[9];
    const float* c2b   = (const float*)d_in[10];
    float* out = (float*)d_out;

    float*    Q    = (float*)d_ws;
    float*    K    = Q + (size_t)NBH*NP*NDK;                // +1,843,200 floats
    u64_t*    amax = (u64_t*)(K + (size_t)NBH*NP*NDK);      // 32*900 u64
    uchar_t*  gidx = (uchar_t*)(amax + (size_t)NBH*NP);     // 32*900*2 B
    ushort_t* Sh   = (ushort_t*)(gidx + (size_t)NBH*NP*2 + 256);  // fp16 scores, 51.84 MB
    ushort_t* S2   = Sh + (size_t)NBH*SSZ;                  // fp16 attn ch-last, 51.84 MB
    ushort_t* w1b  = S2 + (size_t)NB*NP*NP*NH;
    ushort_t* w2b  = w1b + 5*64*8;

    prep_weights_kernel<<<dim3(1), 256, 0, stream>>>(c1w, c2w, w1b, w2b);
    proj_kernel<<<dim3(57, 8, 2), 256, 0, stream>>>(query, key_t, Wq, bq, Wk, bk, Q, K, amax);
    scores_kernel<<<dim3(15, 15, 32), 256, 0, stream>>>(Q, K, Sh, amax);
    decode_kernel<<<dim3(113), 256, 0, stream>>>(amax, gidx);
    modulate_softmax_kernel<<<dim3(900, 4), 256, 0, stream>>>(Sh, gidx, S2, out);
    conv_mfma_kernel<<<dim3(30, 25, 4), 256, 0, stream>>>(S2, w1b, w2b, c1b, c2b, value, out);
}